// Round 2
// baseline (583.259 us; speedup 1.0000x reference)
//
#include <hip/hip_runtime.h>

#define KI 50
#define STR 72

// LDS float layout (stride-72 rows, col c at offset 4+c, ring zeros at 3 / 68):
//  vA [0,2448)       34 rows  (v rows base-1 .. base+32; halo row read from global)
//  vB [2448,4896)    34 rows
//  X0 [0,2736)       38 rows  (x rows base-3 .. base+34) -- overlays vA/vB, phases 0-2 only
//  R  [4896,7344)    34 rows  (r rows base-1 .. base+32)
//  X1 [7344,10080)   38 rows
//  W  [10080,10522)  w2(162) rhb(+162) qw(+171,180) qb(+351,10) fcw(+361,80) rb(+441)
#define VA_OFF 0
#define VB_OFF 2448
#define X0_OFF 0
#define R_OFF 4896
#define X1_OFF 7344
#define W_OFF 10080
#define LDS_TOT 10522

// d_ws float layout: [0,171) w2+rhb; ints at float-off 256: flags[256];
// float-off 1024: slots[256][2][72]  (slot s = (img*2+half)*2+parity)

__global__ void vin_setup(const float* __restrict__ h_w, const float* __restrict__ h_b,
                          const float* __restrict__ r_w, float* __restrict__ ws) {
    int t = threadIdx.x;
    if (t < 162) {
        int i = t / 81, rem = t % 81, dq = rem / 9, ds = rem % 9;
        float s = 0.f;
        for (int m = 0; m < 150; ++m)
            s = fmaf(r_w[m * 9 + dq], h_w[(m * 2 + i) * 9 + ds], s);
        ws[t] = s;
    } else if (t < 171) {
        int dq = t - 162;
        float s = 0.f;
        for (int m = 0; m < 150; ++m)
            s = fmaf(r_w[m * 9 + dq], h_b[m], s);
        ws[t] = s;
    }
    int* flags = (int*)ws + 256;
    if (t < 256) flags[t] = 0;
}

__launch_bounds__(512, 2)
__global__ void vin_main(const float* __restrict__ x,
                         const int* __restrict__ pos_x, const int* __restrict__ pos_y,
                         const float* __restrict__ q_w, const float* __restrict__ q_b,
                         const float* __restrict__ fc_w, const float* __restrict__ r_b,
                         float* __restrict__ ws, float* __restrict__ out) {
    __shared__ __align__(16) float S[LDS_TOT];
    const int tid = threadIdx.x;
    const int img = blockIdx.x & 127;
    const int hf  = blockIdx.x >> 7;     // 0: rows 0..31, 1: rows 32..63
    const int base = hf << 5;
    const int rr = tid >> 4;             // 0..31
    const int c4 = (tid & 15) << 2;      // 0,4,..,60
    float* SW = S + W_OFF;
    int* flags = (int*)ws + 256;
    float* slots = ws + 1024;
    const int self = img * 2 + hf;
    const int partner = img * 2 + (1 - hf);

    // ---- phase 0: zero LDS work regions, load weights, zero own exchange slots
    float4 z4 = make_float4(0.f, 0.f, 0.f, 0.f);
    for (int i = tid; i < 2520; i += 512) ((float4*)S)[i] = z4;   // [0,10080)
    for (int i = tid; i < 171; i += 512) SW[i] = ws[i];
    for (int i = tid; i < 180; i += 512) SW[171 + i] = q_w[i];
    if (tid < 10) SW[351 + tid] = q_b[tid];
    for (int i = tid; i < 80; i += 512) SW[361 + i] = fc_w[i];
    if (tid == 0) SW[441] = r_b[0];
    if (tid < 36) ((float4*)(slots + self * 144))[tid] = z4;      // own 2 slots
    __syncthreads();

    // ---- phase 1: stage x rows [base-3, base+34] ∩ [0,63]  (35 rows, 2 ch)
    {
        const int gstart = hf ? 29 : 0;
        for (int i = tid; i < 1120; i += 512) {
            int ch = i / 560, rem = i - ch * 560;
            int rowi = rem >> 4, cx = (rem & 15) << 2;
            int g = gstart + rowi;
            int lx = g - base + 3;
            float4 v = *(const float4*)(x + (size_t)img * 8192 + ch * 4096 + g * 64 + cx);
            *(float4*)&S[(ch ? X1_OFF : X0_OFF) + lx * STR + 4 + cx] = v;
        }
    }
    __syncthreads();

    // ---- phase 2: r rows base-1..base+32 via composite conv (exact SAME-border clip)
    for (int pass = 0; pass < 2; ++pass) {
        int lr = rr + (pass << 5);
        if (lr < 34) {
            int g = base - 1 + lr;
            if ((unsigned)g <= 63u) {
                float tacc[9][4];
#pragma unroll
                for (int dq = 0; dq < 9; ++dq) {
                    float rh = SW[162 + dq];
#pragma unroll
                    for (int p = 0; p < 4; ++p) tacc[dq][p] = rh;
                }
#pragma unroll
                for (int ch = 0; ch < 2; ++ch) {
                    float xb[5][12];
                    const float* X = S + (ch ? X1_OFF : X0_OFF);
#pragma unroll
                    for (int dy = 0; dy < 5; ++dy) {
#pragma unroll
                        for (int j = 0; j < 3; ++j) {
                            float4 a = *(const float4*)&X[(lr + dy) * STR + c4 + 4 * j];
                            xb[dy][4 * j + 0] = a.x; xb[dy][4 * j + 1] = a.y;
                            xb[dy][4 * j + 2] = a.z; xb[dy][4 * j + 3] = a.w;
                        }
                    }
#pragma unroll
                    for (int dqy = 0; dqy < 3; ++dqy)
#pragma unroll
                        for (int dqx = 0; dqx < 3; ++dqx) {
                            int dq = dqy * 3 + dqx;
                            float w[9];
#pragma unroll
                            for (int ds = 0; ds < 9; ++ds) w[ds] = SW[ch * 81 + dq * 9 + ds];
#pragma unroll
                            for (int p = 0; p < 4; ++p) {
                                float t = tacc[dq][p];
#pragma unroll
                                for (int dsy = 0; dsy < 3; ++dsy)
#pragma unroll
                                    for (int dsx = 0; dsx < 3; ++dsx)
                                        t = fmaf(w[dsy * 3 + dsx], xb[dqy + dsy][p + dqx + dsx + 2], t);
                                tacc[dq][p] = t;
                            }
                        }
                }
                float rbv = SW[441];
                float racc[4] = {rbv, rbv, rbv, rbv};
#pragma unroll
                for (int dqy = 0; dqy < 3; ++dqy) {
                    int qy = g + dqy - 1;
                    bool rok = (unsigned)qy <= 63u;
#pragma unroll
                    for (int dqx = 0; dqx < 3; ++dqx) {
                        int dq = dqy * 3 + dqx;
#pragma unroll
                        for (int p = 0; p < 4; ++p) {
                            int qx = c4 + p + dqx - 1;
                            racc[p] += (rok && (unsigned)qx <= 63u) ? tacc[dq][p] : 0.f;
                        }
                    }
                }
                *(float4*)&S[R_OFF + lr * STR + 4 + c4] =
                    make_float4(racc[0], racc[1], racc[2], racc[3]);
            }
        }
    }
    __syncthreads();

    // ---- phase 3: qr (loop-invariant half of q-conv) into regs; loop weights; zero vA/vB
    float qr[10][4];
    float qwv[10][9];
    {
        float rnb[3][12];
        const float* SR = S + R_OFF;
#pragma unroll
        for (int ky = 0; ky < 3; ++ky) {
#pragma unroll
            for (int j = 0; j < 3; ++j) {
                float4 a = *(const float4*)&SR[(rr + ky) * STR + c4 + 4 * j];
                rnb[ky][4 * j + 0] = a.x; rnb[ky][4 * j + 1] = a.y;
                rnb[ky][4 * j + 2] = a.z; rnb[ky][4 * j + 3] = a.w;
            }
        }
#pragma unroll
        for (int c = 0; c < 10; ++c) {
            float qbc = SW[351 + c];
            float w[9];
#pragma unroll
            for (int j = 0; j < 9; ++j) w[j] = SW[171 + c * 18 + j];
#pragma unroll
            for (int p = 0; p < 4; ++p) {
                float acc = qbc;
#pragma unroll
                for (int ky = 0; ky < 3; ++ky)
#pragma unroll
                    for (int kx = 0; kx < 3; ++kx)
                        acc = fmaf(w[ky * 3 + kx], rnb[ky][p + kx + 3], acc);
                qr[c][p] = acc;
            }
        }
#pragma unroll
        for (int c = 0; c < 10; ++c)
#pragma unroll
            for (int j = 0; j < 9; ++j) qwv[c][j] = SW[171 + c * 18 + 9 + j];
        for (int i = tid; i < 1224; i += 512) ((float4*)S)[i] = z4;   // vA+vB
    }
    __syncthreads();

    // ---- phase 4: 50 VI steps with seam exchange
    const int bRR = hf ? 0 : 31;       // seam thread-row (also reads halo)
    const bool isB = (rr == bRR);
    const int haloDy = hf ? 0 : 2;
    float* cur = S + VA_OFF;
    float* nxt = S + VB_OFF;
#pragma unroll 1
    for (int k = 1; k <= KI; ++k) {
        if (tid == 0) {
            while (__hip_atomic_load(flags + partner, __ATOMIC_ACQUIRE,
                                     __HIP_MEMORY_SCOPE_AGENT) < k - 1)
                __builtin_amdgcn_s_sleep(1);
        }
        __syncthreads();
        const float* slotR = slots + (partner * 2 + ((k - 1) & 1)) * STR;
        float nb[3][12];
#pragma unroll
        for (int dy = 0; dy < 3; ++dy) {
            float4 a0, a1, a2;
            if (isB && dy == haloDy && k > 1) {
                const float4* gp = (const float4*)(slotR + c4);
                a0 = gp[0]; a1 = gp[1]; a2 = gp[2];
            } else {
                const float* lp = cur + (rr + dy) * STR + c4;
                a0 = *(const float4*)lp; a1 = *(const float4*)(lp + 4); a2 = *(const float4*)(lp + 8);
            }
            nb[dy][0] = a0.x; nb[dy][1] = a0.y; nb[dy][2]  = a0.z; nb[dy][3]  = a0.w;
            nb[dy][4] = a1.x; nb[dy][5] = a1.y; nb[dy][6]  = a1.z; nb[dy][7]  = a1.w;
            nb[dy][8] = a2.x; nb[dy][9] = a2.y; nb[dy][10] = a2.z; nb[dy][11] = a2.w;
        }
        float vmax[4];
#pragma unroll
        for (int c = 0; c < 10; ++c) {
#pragma unroll
            for (int p = 0; p < 4; ++p) {
                float acc = qr[c][p];
#pragma unroll
                for (int ky = 0; ky < 3; ++ky)
#pragma unroll
                    for (int kx = 0; kx < 3; ++kx)
                        acc = fmaf(qwv[c][ky * 3 + kx], nb[ky][p + kx + 3], acc);
                vmax[p] = c ? fmaxf(vmax[p], acc) : acc;
            }
        }
        float4 vv = make_float4(vmax[0], vmax[1], vmax[2], vmax[3]);
        *(float4*)&nxt[(rr + 1) * STR + 4 + c4] = vv;
        if (isB) *(float4*)(slots + (self * 2 + (k & 1)) * STR + 4 + c4) = vv;
        __syncthreads();
        if (tid == 0) {
            __threadfence();
            __hip_atomic_store(flags + self, k, __ATOMIC_RELEASE, __HIP_MEMORY_SCOPE_AGENT);
        }
        float* t = cur; cur = nxt; nxt = t;
    }

    // ---- phase 5: readout at (pos_x, pos_y) + FC by the owning thread
    if (tid == 0) {
        while (__hip_atomic_load(flags + partner, __ATOMIC_ACQUIRE,
                                 __HIP_MEMORY_SCOPE_AGENT) < KI)
            __builtin_amdgcn_s_sleep(1);
    }
    __syncthreads();
    int pr = pos_x[img], pc = pos_y[img];
    if ((pr >> 5) == hf) {
        int rloc = pr - base;
        if (tid == rloc * 16 + (pc >> 2)) {
            const float* slotF = slots + (partner * 2 + 0) * STR;   // k=50 parity
            int p = pc & 3;
            float qf[10];
#pragma unroll
            for (int c = 0; c < 10; ++c) {
                float acc = qr[c][p];
#pragma unroll
                for (int ky = 0; ky < 3; ++ky) {
                    int vr = rloc + ky;
                    bool halo = hf ? (vr == 0) : (vr == 33);
#pragma unroll
                    for (int kx = 0; kx < 3; ++kx) {
                        int off = 4 + pc + kx - 1;
                        float vvv = halo ? slotF[off] : cur[vr * STR + off];
                        acc = fmaf(qwv[c][ky * 3 + kx], vvv, acc);
                    }
                }
                qf[c] = acc;
            }
#pragma unroll
            for (int o = 0; o < 8; ++o) {
                float s = 0.f;
#pragma unroll
                for (int c = 0; c < 10; ++c) s = fmaf(SW[361 + o * 10 + c], qf[c], s);
                out[img * 8 + o] = s;
            }
        }
    }
}

extern "C" void kernel_launch(void* const* d_in, const int* in_sizes, int n_in,
                              void* d_out, int out_size, void* d_ws, size_t ws_size,
                              hipStream_t stream) {
    const float* x     = (const float*)d_in[0];
    const int*   pos_x = (const int*)d_in[1];
    const int*   pos_y = (const int*)d_in[2];
    const float* h_w   = (const float*)d_in[3];
    const float* h_b   = (const float*)d_in[4];
    const float* r_w   = (const float*)d_in[5];
    const float* r_b   = (const float*)d_in[6];
    const float* q_w   = (const float*)d_in[7];
    const float* q_b   = (const float*)d_in[8];
    const float* fc_w  = (const float*)d_in[9];
    float* ws  = (float*)d_ws;
    float* out = (float*)d_out;

    vin_setup<<<1, 512, 0, stream>>>(h_w, h_b, r_w, ws);
    vin_main<<<256, 512, 0, stream>>>(x, pos_x, pos_y, q_w, q_b, fc_w, r_b, ws, out);
}

// Round 3
// 219.685 us; speedup vs baseline: 2.6550x; 2.6550x over previous
//
#include <hip/hip_runtime.h>

#define KI 50

// LDS float layout (stride-68 rows, 16B-aligned row starts since 68*4=272=17*16):
//  X0 [0,4624)      68x68: x ch0, x(g,cx) at (g+2, cx+2)  -- reused as vA: v(g,c) at (g+1, c+2)
//  X1 [4624,9248)   68x68: x ch1                          -- reused as vB
//  R  [9248,13736)  66x68: r(g,c) at (g+1, c+2)
//  W  [13736,14178) w2[162] rhb@+162(9) qw@+171(180) qb@+351(10) fcw@+361(80) rb@+441
#define X1_OFF 4624
#define R_OFF 9248
#define W_OFF 13736
#define LDS_TOT 14178

__device__ __forceinline__ void vi_step(const float* __restrict__ cur, float* __restrict__ nxt,
                                        int row, int c0,
                                        const float (&qr)[10][8], const float (&qwv)[10][9]) {
    float nb[3][12];
#pragma unroll
    for (int dy = 0; dy < 3; ++dy) {
        const float* lp = cur + (row + dy) * 68 + c0;
        float4 a0 = *(const float4*)lp;
        float4 a1 = *(const float4*)(lp + 4);
        float4 a2 = *(const float4*)(lp + 8);
        nb[dy][0] = a0.x; nb[dy][1] = a0.y; nb[dy][2]  = a0.z; nb[dy][3]  = a0.w;
        nb[dy][4] = a1.x; nb[dy][5] = a1.y; nb[dy][6]  = a1.z; nb[dy][7]  = a1.w;
        nb[dy][8] = a2.x; nb[dy][9] = a2.y; nb[dy][10] = a2.z; nb[dy][11] = a2.w;
    }
    float vmax[8];
#pragma unroll
    for (int c = 0; c < 10; ++c) {
#pragma unroll
        for (int p = 0; p < 8; ++p) {
            float acc = qr[c][p];
#pragma unroll
            for (int ky = 0; ky < 3; ++ky)
#pragma unroll
                for (int kx = 0; kx < 3; ++kx)
                    acc = fmaf(qwv[c][ky * 3 + kx], nb[ky][p + kx + 1], acc);
            vmax[p] = c ? fmaxf(vmax[p], acc) : acc;
        }
    }
    float* wp = nxt + (row + 1) * 68 + 2 + c0;   // 8B-aligned
#pragma unroll
    for (int j = 0; j < 4; ++j)
        *(float2*)(wp + 2 * j) = make_float2(vmax[2 * j], vmax[2 * j + 1]);
}

__launch_bounds__(512, 2)
__global__ void vin_main(const float* __restrict__ x,
                         const int* __restrict__ pos_x, const int* __restrict__ pos_y,
                         const float* __restrict__ h_w, const float* __restrict__ h_b,
                         const float* __restrict__ r_w, const float* __restrict__ r_b,
                         const float* __restrict__ q_w, const float* __restrict__ q_b,
                         const float* __restrict__ fc_w, float* __restrict__ out) {
    __shared__ __align__(16) float S[LDS_TOT];
    const int tid = threadIdx.x;
    const int b = blockIdx.x;
    const int row = tid >> 3;          // 0..63
    const int c0 = (tid & 7) << 3;     // 0,8,..,56
    float* SW = S + W_OFF;

    // ---- phase 0: zero X0/X1/R (rings + interiors); 13736 floats = 3434 quads
    float4 z4 = make_float4(0.f, 0.f, 0.f, 0.f);
    for (int i = tid; i < 3434; i += 512) ((float4*)S)[i] = z4;
    __syncthreads();

    // ---- phase 1: stage x interior; compute composite weights w2/rhb; load loop weights
    {
        const float4* xg = (const float4*)(x + (size_t)b * 8192);
        for (int i = tid; i < 2048; i += 512) {
            float4 v = xg[i];
            int ch = i >> 10, rem = i & 1023;
            int y = rem >> 4, xc = (rem & 15) << 2;
            float* dst = S + ch * 4624 + (y + 2) * 68 + xc + 2;   // 8B-aligned
            *(float2*)dst       = make_float2(v.x, v.y);
            *(float2*)(dst + 2) = make_float2(v.z, v.w);
        }
    }
    if (tid < 162) {
        int i = tid / 81, rem = tid % 81, dq = rem / 9, ds = rem % 9;
        float s = 0.f;
        for (int m = 0; m < 150; ++m)
            s = fmaf(r_w[m * 9 + dq], h_w[(m * 2 + i) * 9 + ds], s);
        SW[tid] = s;
    } else if (tid < 171) {
        int dq = tid - 162;
        float s = 0.f;
        for (int m = 0; m < 150; ++m)
            s = fmaf(r_w[m * 9 + dq], h_b[m], s);
        SW[tid] = s;
    } else if (tid < 351) {
        SW[tid] = q_w[tid - 171];
    } else if (tid < 361) {
        SW[tid] = q_b[tid - 351];
    } else if (tid < 441) {
        SW[tid] = fc_w[tid - 361];
    } else if (tid == 441) {
        SW[441] = r_b[0];
    }
    __syncthreads();

    // ---- phase 2: r = composite 2-stage conv (exact SAME-border clip on the hidden layer)
    {
        float xb0[5][12], xb1[5][12];
        const float* X0 = S;
        const float* X1 = S + X1_OFF;
#pragma unroll
        for (int dy = 0; dy < 5; ++dy) {
#pragma unroll
            for (int j = 0; j < 3; ++j) {
                float4 a = *(const float4*)&X0[(row + dy) * 68 + c0 + 4 * j];
                xb0[dy][4 * j + 0] = a.x; xb0[dy][4 * j + 1] = a.y;
                xb0[dy][4 * j + 2] = a.z; xb0[dy][4 * j + 3] = a.w;
                float4 c = *(const float4*)&X1[(row + dy) * 68 + c0 + 4 * j];
                xb1[dy][4 * j + 0] = c.x; xb1[dy][4 * j + 1] = c.y;
                xb1[dy][4 * j + 2] = c.z; xb1[dy][4 * j + 3] = c.w;
            }
        }
        float racc[8];
        float rbv = SW[441];
#pragma unroll
        for (int p = 0; p < 8; ++p) racc[p] = rbv;
#pragma unroll
        for (int dqy = 0; dqy < 3; ++dqy) {
            bool rowok = (row + dqy >= 1) && (row + dqy <= 64);
#pragma unroll
            for (int dqx = 0; dqx < 3; ++dqx) {
                int dq = dqy * 3 + dqx;
                float rh = SW[162 + dq];
                float w20[9], w21[9];
#pragma unroll
                for (int ds = 0; ds < 9; ++ds) {
                    w20[ds] = SW[dq * 9 + ds];
                    w21[ds] = SW[81 + dq * 9 + ds];
                }
#pragma unroll
                for (int p = 0; p < 8; ++p) {
                    float t = rh;
#pragma unroll
                    for (int dsy = 0; dsy < 3; ++dsy)
#pragma unroll
                        for (int dsx = 0; dsx < 3; ++dsx) {
                            int ds = dsy * 3 + dsx;
                            t = fmaf(w20[ds], xb0[dqy + dsy][p + dqx + dsx], t);
                            t = fmaf(w21[ds], xb1[dqy + dsy][p + dqx + dsx], t);
                        }
                    int qx = c0 + p + dqx - 1;
                    bool ok = rowok && (qx >= 0) && (qx < 64);
                    racc[p] += ok ? t : 0.f;
                }
            }
        }
#pragma unroll
        for (int p = 0; p < 8; ++p)
            S[R_OFF + (row + 1) * 68 + 2 + c0 + p] = racc[p];
    }
    __syncthreads();

    // ---- phase 3: qr (loop-invariant q half) + loop weights into regs; re-zero vA/vB
    float qr[10][8];
    float qwv[10][9];
    {
        float rnb[3][12];
        const float* SR = S + R_OFF;
#pragma unroll
        for (int ky = 0; ky < 3; ++ky) {
            const float* lp = SR + (row + ky) * 68 + c0;
            float4 a0 = *(const float4*)lp;
            float4 a1 = *(const float4*)(lp + 4);
            float4 a2 = *(const float4*)(lp + 8);
            rnb[ky][0] = a0.x; rnb[ky][1] = a0.y; rnb[ky][2]  = a0.z; rnb[ky][3]  = a0.w;
            rnb[ky][4] = a1.x; rnb[ky][5] = a1.y; rnb[ky][6]  = a1.z; rnb[ky][7]  = a1.w;
            rnb[ky][8] = a2.x; rnb[ky][9] = a2.y; rnb[ky][10] = a2.z; rnb[ky][11] = a2.w;
        }
#pragma unroll
        for (int c = 0; c < 10; ++c) {
            float qbc = SW[351 + c];
            float w[9];
#pragma unroll
            for (int j = 0; j < 9; ++j) w[j] = SW[171 + c * 18 + j];
#pragma unroll
            for (int p = 0; p < 8; ++p) {
                float acc = qbc;
#pragma unroll
                for (int ky = 0; ky < 3; ++ky)
#pragma unroll
                    for (int kx = 0; kx < 3; ++kx)
                        acc = fmaf(w[ky * 3 + kx], rnb[ky][p + kx + 1], acc);
                qr[c][p] = acc;
            }
        }
#pragma unroll
        for (int c = 0; c < 10; ++c)
#pragma unroll
            for (int j = 0; j < 9; ++j) qwv[c][j] = SW[171 + c * 18 + 9 + j];
        // re-zero vA/vB region (held x data); v0 = 0, rings stay 0 forever
        for (int i = tid; i < 2312; i += 512) ((float4*)S)[i] = z4;
    }
    __syncthreads();

    // ---- phase 4: 50 VI steps, double-buffered v in LDS (ends in vA)
    float* vA = S;
    float* vB = S + X1_OFF;
#pragma unroll 1
    for (int k = 0; k < KI / 2; ++k) {
        vi_step(vA, vB, row, c0, qr, qwv);
        __syncthreads();
        vi_step(vB, vA, row, c0, qr, qwv);
        __syncthreads();
    }

    // ---- phase 5: readout at (pos_x, pos_y) + FC by the owning thread
    int pr = pos_x[b], pc = pos_y[b];
    if (row == pr && (pc >> 3) == (tid & 7)) {
        int p = pc & 7;
        float qf[10];
#pragma unroll
        for (int c = 0; c < 10; ++c) {
            float acc = qr[c][p];
#pragma unroll
            for (int ky = 0; ky < 3; ++ky)
#pragma unroll
                for (int kx = 0; kx < 3; ++kx)
                    acc = fmaf(qwv[c][3 * ky + kx], vA[(pr + ky) * 68 + pc + 1 + kx], acc);
            qf[c] = acc;
        }
#pragma unroll
        for (int o = 0; o < 8; ++o) {
            float s = 0.f;
#pragma unroll
            for (int c = 0; c < 10; ++c) s = fmaf(SW[361 + o * 10 + c], qf[c], s);
            out[b * 8 + o] = s;
        }
    }
}

extern "C" void kernel_launch(void* const* d_in, const int* in_sizes, int n_in,
                              void* d_out, int out_size, void* d_ws, size_t ws_size,
                              hipStream_t stream) {
    const float* x     = (const float*)d_in[0];
    const int*   pos_x = (const int*)d_in[1];
    const int*   pos_y = (const int*)d_in[2];
    const float* h_w   = (const float*)d_in[3];
    const float* h_b   = (const float*)d_in[4];
    const float* r_w   = (const float*)d_in[5];
    const float* r_b   = (const float*)d_in[6];
    const float* q_w   = (const float*)d_in[7];
    const float* q_b   = (const float*)d_in[8];
    const float* fc_w  = (const float*)d_in[9];
    float* out = (float*)d_out;

    vin_main<<<128, 512, 0, stream>>>(x, pos_x, pos_y, h_w, h_b, r_w, r_b,
                                      q_w, q_b, fc_w, out);
}